// Round 3
// baseline (352.993 us; speedup 1.0000x reference)
//
#include <hip/hip_runtime.h>
#include <hip/hip_fp16.h>
#include <math.h>

#define N_NODES 50000
#define N_EDGES 400000
#define NUM_GRAPHS 64

// ---------------------------------------------------------------------------
// Factorized NNConv with fp16 gather tables:
//   msg[e,o] = sum_j relu(a_e*w1_j+b1_j) * P[src,j,o] + Q[src,o]
//   P[n,j,o] = sum_i x[n,i]*w2[j, i*O+o]  -- node-level GEMM, never per-edge
// P1 (half, 192 cols/node): [0,160)=P(j,o) o<16, [160,176)=Q, [176,192)=x@root
// P2 (half, 384 cols/node): [0,320)=P(j,o) o<32, [320,352)=Q, [352,384)=h1@root
// h1 is never materialized (fused into k4); h2 never materialized (fused k7).
// ---------------------------------------------------------------------------

__global__ __launch_bounds__(256) void k1_p1(const float* __restrict__ x,
        const float* __restrict__ w2, const float* __restrict__ b2,
        const float* __restrict__ root, __half* __restrict__ P) {
    __shared__ float Wl[32][192];
    __shared__ float xl[16][32];
    int t = threadIdx.x;
    for (int idx = t; idx < 32 * 192; idx += 256) {
        int i = idx / 192, c = idx % 192;
        float w;
        if (c < 160)      { int j = c >> 4;  int o = c & 15;  w = w2[j * 512 + i * 16 + o]; }
        else if (c < 176) { w = b2[i * 16 + (c - 160)]; }
        else              { w = root[i * 16 + (c - 176)]; }
        Wl[i][c] = w;
    }
    int n0 = blockIdx.x * 16;
    for (int idx = t; idx < 16 * 32; idx += 256) {
        int nl = idx >> 5, i = idx & 31;
        int n = n0 + nl;
        xl[nl][i] = (n < N_NODES) ? x[n * 32 + i] : 0.f;
    }
    __syncthreads();
    int nl = t >> 4, l = t & 15;
    int n = n0 + nl;
    if (n >= N_NODES) return;
    float a0[6], a1[6];
#pragma unroll
    for (int k = 0; k < 6; k++) { a0[k] = 0.f; a1[k] = 0.f; }
#pragma unroll
    for (int i = 0; i < 32; i++) {
        float xv = xl[nl][i];
#pragma unroll
        for (int k = 0; k < 6; k++) {
            a0[k] += xv * Wl[i][2 * l + 32 * k];
            a1[k] += xv * Wl[i][2 * l + 1 + 32 * k];
        }
    }
    __half2* Po = (__half2*)(P + (size_t)n * 192);
#pragma unroll
    for (int k = 0; k < 6; k++) Po[l + 16 * k] = __floats2half2_rn(a0[k], a1[k]);
}

// fused: h1 = elu(agg1/cnt + root-term + bias) computed in prologue (never stored)
__global__ __launch_bounds__(256) void k4_p2(const float* __restrict__ agg1,
        const float* __restrict__ cnt, const __half* __restrict__ P1,
        const float* __restrict__ bias1,
        const float* __restrict__ w2, const float* __restrict__ b2,
        const float* __restrict__ root, __half* __restrict__ P2) {
    __shared__ float Wl[16][384];
    __shared__ float hl[16][16];
    int t = threadIdx.x;
    for (int idx = t; idx < 16 * 384; idx += 256) {
        int i = idx / 384, c = idx % 384;
        float w;
        if (c < 320)      { int j = c >> 5;  int o = c & 31;  w = w2[j * 512 + i * 32 + o]; }
        else if (c < 352) { w = b2[i * 32 + (c - 320)]; }
        else              { w = root[i * 32 + (c - 352)]; }
        Wl[i][c] = w;
    }
    int n0 = blockIdx.x * 16;
    {
        int nl = t >> 4, i = t & 15;
        int n = n0 + nl;
        float v = 0.f;
        if (n < N_NODES) {
            float c = fmaxf(cnt[n], 1.0f);
            v = agg1[n * 16 + i] / c + __half2float(P1[(size_t)n * 192 + 176 + i]) + bias1[i];
            v = v > 0.f ? v : expm1f(v);
        }
        hl[nl][i] = v;
    }
    __syncthreads();
    int nl = t >> 4, l = t & 15;
    int n = n0 + nl;
    if (n >= N_NODES) return;
    float a0[12], a1[12];
#pragma unroll
    for (int k = 0; k < 12; k++) { a0[k] = 0.f; a1[k] = 0.f; }
#pragma unroll
    for (int i = 0; i < 16; i++) {
        float hv = hl[nl][i];
#pragma unroll
        for (int k = 0; k < 12; k++) {
            a0[k] += hv * Wl[i][2 * l + 32 * k];
            a1[k] += hv * Wl[i][2 * l + 1 + 32 * k];
        }
    }
    __half2* Po = (__half2*)(P2 + (size_t)n * 384);
#pragma unroll
    for (int k = 0; k < 12; k++) Po[l + 16 * k] = __floats2half2_rn(a0[k], a1[k]);
}

// 8 lanes/edge, each lane handles 2 output cols via half2 (64B/j coalesced per edge)
__global__ __launch_bounds__(256) void k2_edge1(const __half* __restrict__ P,
        const int* __restrict__ src, const int* __restrict__ dst,
        const float* __restrict__ ea, const float* __restrict__ w1,
        const float* __restrict__ b1, float* __restrict__ agg,
        float* __restrict__ cnt) {
    int t = threadIdx.x;
    int e = blockIdx.x * 32 + (t >> 3);
    int l = t & 7;
    if (e >= N_EDGES) return;
    float a = ea[e];
    int s = src[e], d = dst[e];
    const __half2* Pr = (const __half2*)(P + (size_t)s * 192);
    float r[10];
#pragma unroll
    for (int j = 0; j < 10; j++) r[j] = fmaxf(a * w1[j] + b1[j], 0.f);
    float2 q = __half22float2(Pr[80 + l]);
    float m0 = q.x, m1 = q.y;
#pragma unroll
    for (int j = 0; j < 10; j++) {
        float2 p = __half22float2(Pr[j * 8 + l]);
        m0 += r[j] * p.x;
        m1 += r[j] * p.y;
    }
    atomicAdd(agg + d * 16 + 2 * l, m0);
    atomicAdd(agg + d * 16 + 2 * l + 1, m1);
    if (l == 0) atomicAdd(cnt + d, 1.0f);
}

// 16 lanes/edge, half2 per lane
__global__ __launch_bounds__(256) void k5_edge2(const __half* __restrict__ P,
        const int* __restrict__ src, const int* __restrict__ dst,
        const float* __restrict__ ea, const float* __restrict__ w1,
        const float* __restrict__ b1, float* __restrict__ agg) {
    int t = threadIdx.x;
    int e = blockIdx.x * 16 + (t >> 4);
    int l = t & 15;
    if (e >= N_EDGES) return;
    float a = ea[e];
    int s = src[e], d = dst[e];
    const __half2* Pr = (const __half2*)(P + (size_t)s * 384);
    float r[10];
#pragma unroll
    for (int j = 0; j < 10; j++) r[j] = fmaxf(a * w1[j] + b1[j], 0.f);
    float2 q = __half22float2(Pr[160 + l]);
    float m0 = q.x, m1 = q.y;
#pragma unroll
    for (int j = 0; j < 10; j++) {
        float2 p = __half22float2(Pr[j * 16 + l]);
        m0 += r[j] * p.x;
        m1 += r[j] * p.y;
    }
    atomicAdd(agg + d * 32 + 2 * l, m0);
    atomicAdd(agg + d * 32 + 2 * l + 1, m1);
}

// fused: h2 computed inline during pooling (never stored).
// batch is sorted -> each graph is a contiguous node range; binary search, no atomics
__global__ __launch_bounds__(256) void k7_pool(const float* __restrict__ agg2,
        const float* __restrict__ cnt, const __half* __restrict__ P2,
        const float* __restrict__ bias2, const int* __restrict__ batch,
        float* __restrict__ gp) {
    int g = blockIdx.x;
    int t = threadIdx.x;
    int lo = 0, hi = N_NODES;
    while (lo < hi) { int mid = (lo + hi) >> 1; if (batch[mid] < g) lo = mid + 1; else hi = mid; }
    int start = lo;
    hi = N_NODES;
    while (lo < hi) { int mid = (lo + hi) >> 1; if (batch[mid] < g + 1) lo = mid + 1; else hi = mid; }
    int end = lo;
    int o = t & 31, ch = t >> 5;
    float s = 0.f;
    for (int n = start + ch; n < end; n += 8) {
        float c = fmaxf(cnt[n], 1.0f);
        float v = agg2[(size_t)n * 32 + o] / c
                + __half2float(P2[(size_t)n * 384 + 352 + o]) + bias2[o];
        s += v > 0.f ? v : expm1f(v);
    }
    __shared__ float red[8][32];
    red[ch][o] = s;
    __syncthreads();
    if (t < 32) {
        float tot = 0.f;
#pragma unroll
        for (int c = 0; c < 8; c++) tot += red[c][t];
        gp[g * 32 + t] = tot / fmaxf((float)(end - start), 1.0f);
    }
}

__global__ __launch_bounds__(256) void k8_head(const float* __restrict__ gp,
        const float* __restrict__ fc1w, const float* __restrict__ fc1b,
        const float* __restrict__ fc2w, const float* __restrict__ fc2b,
        float* __restrict__ out) {
    __shared__ float gl[64][32];
    __shared__ float w1l[32][64];
    __shared__ float hl[64][64];
    __shared__ float zl[64][2];
    int t = threadIdx.x;
    for (int idx = t; idx < 64 * 32; idx += 256) gl[idx >> 5][idx & 31] = gp[idx];
    for (int idx = t; idx < 32 * 64; idx += 256) w1l[idx >> 6][idx & 63] = fc1w[idx];
    __syncthreads();
    for (int idx = t; idx < 64 * 64; idx += 256) {
        int gg = idx >> 6, c = idx & 63;
        float acc = fc1b[c];
#pragma unroll
        for (int i = 0; i < 32; i++) acc += gl[gg][i] * w1l[i][c];
        hl[gg][c] = acc > 0.f ? acc : expm1f(acc);
    }
    __syncthreads();
    if (t < 128) {
        int gg = t >> 1, k = t & 1;
        float acc = fc2b[k];
#pragma unroll
        for (int c = 0; c < 64; c++) acc += hl[gg][c] * fc2w[c * 2 + k];
        zl[gg][k] = acc;
    }
    __syncthreads();
    if (t < 128) {
        int gg = t >> 1, k = t & 1;
        float z0 = zl[gg][0], z1 = zl[gg][1];
        float m = fmaxf(z0, z1);
        float lse = m + logf(expf(z0 - m) + expf(z1 - m));
        out[t] = zl[gg][k] - lse;
    }
}

extern "C" void kernel_launch(void* const* d_in, const int* in_sizes, int n_in,
                              void* d_out, int out_size, void* d_ws, size_t ws_size,
                              hipStream_t stream) {
    const float* x       = (const float*)d_in[0];
    const int*   ei      = (const int*)d_in[1];
    const float* ea      = (const float*)d_in[2];
    const int*   batch   = (const int*)d_in[3];
    const float* nn1_w1  = (const float*)d_in[4];
    const float* nn1_b1  = (const float*)d_in[5];
    const float* nn1_w2  = (const float*)d_in[6];
    const float* nn1_b2  = (const float*)d_in[7];
    const float* c1_root = (const float*)d_in[8];
    const float* c1_bias = (const float*)d_in[9];
    const float* nn2_w1  = (const float*)d_in[10];
    const float* nn2_b1  = (const float*)d_in[11];
    const float* nn2_w2  = (const float*)d_in[12];
    const float* nn2_b2  = (const float*)d_in[13];
    const float* c2_root = (const float*)d_in[14];
    const float* c2_bias = (const float*)d_in[15];
    const float* fc1w    = (const float*)d_in[16];
    const float* fc1b    = (const float*)d_in[17];
    const float* fc2w    = (const float*)d_in[18];
    const float* fc2b    = (const float*)d_in[19];
    const int* src = ei;
    const int* dst = ei + N_EDGES;

    char* ws = (char*)d_ws;
    __half* P1 = (__half*)ws;                          // 50000*192*2 = 19.2 MB
    __half* P2 = (__half*)(ws + (size_t)N_NODES * 192 * 2);  // 50000*384*2 = 38.4 MB
    float* fbase = (float*)(ws + (size_t)N_NODES * 192 * 2 + (size_t)N_NODES * 384 * 2);
    float* cnt  = fbase;                                // 50000
    float* agg1 = cnt + N_NODES;                        // 800000
    float* agg2 = agg1 + (size_t)N_NODES * 16;          // 1600000
    float* gp   = agg2 + (size_t)N_NODES * 32;          // 2048

    // cnt, agg1, agg2 are contiguous: one memset
    hipMemsetAsync(cnt, 0, (size_t)(N_NODES + N_NODES * 16 + N_NODES * 32) * sizeof(float), stream);

    k1_p1<<<(N_NODES + 15) / 16, 256, 0, stream>>>(x, nn1_w2, nn1_b2, c1_root, P1);
    k2_edge1<<<(N_EDGES + 31) / 32, 256, 0, stream>>>(P1, src, dst, ea, nn1_w1, nn1_b1, agg1, cnt);
    k4_p2<<<(N_NODES + 15) / 16, 256, 0, stream>>>(agg1, cnt, P1, c1_bias, nn2_w2, nn2_b2, c2_root, P2);
    k5_edge2<<<(N_EDGES + 15) / 16, 256, 0, stream>>>(P2, src, dst, ea, nn2_w1, nn2_b1, agg2);
    k7_pool<<<NUM_GRAPHS, 256, 0, stream>>>(agg2, cnt, P2, c2_bias, batch, gp);
    k8_head<<<1, 256, 0, stream>>>(gp, fc1w, fc1b, fc2w, fc2b, (float*)d_out);
}

// Round 4
// 310.466 us; speedup vs baseline: 1.1370x; 1.1370x over previous
//
#include <hip/hip_runtime.h>
#include <hip/hip_fp16.h>
#include <math.h>

#define N_NODES 50000
#define N_EDGES 400000
#define NUM_GRAPHS 64

// ---------------------------------------------------------------------------
// Factorized NNConv, fp16 tables in COLUMN-MAJOR-PER-NODE layout:
//   msg[e,o] = sum_j relu(a_e*w1_j+b1_j) * P[src,j,o] + Q[src,o]
// P1: per node, 16 cols x 12 half items {P[j=0..9][o], Q[o], R[o]}  (384 B/row)
// P2: per node, 32 cols x 12 half items                              (768 B/row)
// R = x@root (layer1) / h1@root (layer2), consumed at node finalize.
// Edge lane o reads its col's 24 B as 3 independent float2 loads (ILP),
// one fp32 atomic per lane -> one write-through per 64/128B agg line per edge.
// ---------------------------------------------------------------------------

__global__ __launch_bounds__(256) void k1_p1(const float* __restrict__ x,
        const float* __restrict__ w2, const float* __restrict__ b2,
        const float* __restrict__ root, __half* __restrict__ P) {
    __shared__ float Wl[32][192];   // [i][m*16+o]
    __shared__ float xl[16][32];
    int t = threadIdx.x;
    for (int idx = t; idx < 32 * 192; idx += 256) {
        int i = idx / 192, c = idx % 192;
        int m = c >> 4, o = c & 15;
        float w;
        if (m < 10)       w = w2[m * 512 + i * 16 + o];
        else if (m == 10) w = b2[i * 16 + o];
        else              w = root[i * 16 + o];
        Wl[i][c] = w;
    }
    int n0 = blockIdx.x * 16;
    for (int idx = t; idx < 16 * 32; idx += 256) {
        int nl = idx >> 5, i = idx & 31;
        int n = n0 + nl;
        xl[nl][i] = (n < N_NODES) ? x[n * 32 + i] : 0.f;
    }
    __syncthreads();
    int nl = t >> 4, o = t & 15;
    int n = n0 + nl;
    if (n >= N_NODES) return;
    float acc[12];
#pragma unroll
    for (int m = 0; m < 12; m++) acc[m] = 0.f;
#pragma unroll
    for (int i = 0; i < 32; i++) {
        float xv = xl[nl][i];
#pragma unroll
        for (int m = 0; m < 12; m++) acc[m] += xv * Wl[i][m * 16 + o];
    }
    __half2* Po = (__half2*)(P + (size_t)n * 192 + o * 12);
#pragma unroll
    for (int k = 0; k < 6; k++) Po[k] = __floats2half2_rn(acc[2 * k], acc[2 * k + 1]);
}

// fused: h1 = elu(agg1/cnt + R1 + bias1) computed in prologue (never stored)
__global__ __launch_bounds__(256) void k4_p2(const float* __restrict__ agg1,
        const float* __restrict__ cnt, const __half* __restrict__ P1,
        const float* __restrict__ bias1,
        const float* __restrict__ w2, const float* __restrict__ b2,
        const float* __restrict__ root, __half* __restrict__ P2) {
    __shared__ float Wl[16][384];   // [i][m*32+o]
    __shared__ float hl[8][16];
    int t = threadIdx.x;
    for (int idx = t; idx < 16 * 384; idx += 256) {
        int i = idx / 384, c = idx % 384;
        int m = c >> 5, o = c & 31;
        float w;
        if (m < 10)       w = w2[m * 512 + i * 32 + o];
        else if (m == 10) w = b2[i * 32 + o];
        else              w = root[i * 32 + o];
        Wl[i][c] = w;
    }
    int n0 = blockIdx.x * 8;
    if (t < 128) {
        int nl = t >> 4, i = t & 15;
        int n = n0 + nl;
        float v = 0.f;
        if (n < N_NODES) {
            float c = fmaxf(cnt[n], 1.0f);
            v = agg1[n * 16 + i] / c
              + __half2float(P1[(size_t)n * 192 + i * 12 + 11]) + bias1[i];
            v = v > 0.f ? v : expm1f(v);
        }
        hl[nl][i] = v;
    }
    __syncthreads();
    int nl = t >> 5, o = t & 31;
    int n = n0 + nl;
    if (n >= N_NODES) return;
    float acc[12];
#pragma unroll
    for (int m = 0; m < 12; m++) acc[m] = 0.f;
#pragma unroll
    for (int i = 0; i < 16; i++) {
        float hv = hl[nl][i];
#pragma unroll
        for (int m = 0; m < 12; m++) acc[m] += hv * Wl[i][m * 32 + o];
    }
    __half2* Po = (__half2*)(P2 + (size_t)n * 384 + o * 12);
#pragma unroll
    for (int k = 0; k < 6; k++) Po[k] = __floats2half2_rn(acc[2 * k], acc[2 * k + 1]);
}

// conv1 edges: 16 lanes/edge, 3 independent float2 loads, 1 atomic/lane (64B/edge)
__global__ __launch_bounds__(256) void k2_edge1(const __half* __restrict__ P,
        const int* __restrict__ src, const int* __restrict__ dst,
        const float* __restrict__ ea, const float* __restrict__ w1,
        const float* __restrict__ b1, float* __restrict__ agg,
        float* __restrict__ cnt) {
    int t = threadIdx.x;
    int e = blockIdx.x * 16 + (t >> 4);
    int o = t & 15;
    if (e >= N_EDGES) return;
    float a = ea[e];
    int s = src[e], d = dst[e];
    const float2* Pf = (const float2*)P;
    int base = s * 48 + o * 3;
    float2 f0 = Pf[base];
    float2 f1 = Pf[base + 1];
    float2 f2 = Pf[base + 2];
    float r[10];
#pragma unroll
    for (int j = 0; j < 10; j++) r[j] = fmaxf(a * w1[j] + b1[j], 0.f);
    union { float2 f; __half2 h[2]; } u;
    float m;
    {
        u.f = f2;                       // items (8,9) (Q,R)
        float2 p89 = __half22float2(u.h[0]);
        float2 pQR = __half22float2(u.h[1]);
        m = pQR.x + r[8] * p89.x + r[9] * p89.y;
    }
    {
        u.f = f0;                       // items (0,1) (2,3)
        float2 p01 = __half22float2(u.h[0]);
        float2 p23 = __half22float2(u.h[1]);
        m += r[0] * p01.x + r[1] * p01.y + r[2] * p23.x + r[3] * p23.y;
    }
    {
        u.f = f1;                       // items (4,5) (6,7)
        float2 p45 = __half22float2(u.h[0]);
        float2 p67 = __half22float2(u.h[1]);
        m += r[4] * p45.x + r[5] * p45.y + r[6] * p67.x + r[7] * p67.y;
    }
    atomicAdd(agg + d * 16 + o, m);
    if (o == 0) atomicAdd(cnt + d, 1.0f);
}

// conv2 edges: 32 lanes/edge, 3 independent float2 loads, 1 atomic/lane (128B/edge)
__global__ __launch_bounds__(256) void k5_edge2(const __half* __restrict__ P,
        const int* __restrict__ src, const int* __restrict__ dst,
        const float* __restrict__ ea, const float* __restrict__ w1,
        const float* __restrict__ b1, float* __restrict__ agg) {
    int t = threadIdx.x;
    int e = blockIdx.x * 8 + (t >> 5);
    int o = t & 31;
    if (e >= N_EDGES) return;
    float a = ea[e];
    int s = src[e], d = dst[e];
    const float2* Pf = (const float2*)P;
    int base = s * 96 + o * 3;
    float2 f0 = Pf[base];
    float2 f1 = Pf[base + 1];
    float2 f2 = Pf[base + 2];
    float r[10];
#pragma unroll
    for (int j = 0; j < 10; j++) r[j] = fmaxf(a * w1[j] + b1[j], 0.f);
    union { float2 f; __half2 h[2]; } u;
    float m;
    {
        u.f = f2;
        float2 p89 = __half22float2(u.h[0]);
        float2 pQR = __half22float2(u.h[1]);
        m = pQR.x + r[8] * p89.x + r[9] * p89.y;
    }
    {
        u.f = f0;
        float2 p01 = __half22float2(u.h[0]);
        float2 p23 = __half22float2(u.h[1]);
        m += r[0] * p01.x + r[1] * p01.y + r[2] * p23.x + r[3] * p23.y;
    }
    {
        u.f = f1;
        float2 p45 = __half22float2(u.h[0]);
        float2 p67 = __half22float2(u.h[1]);
        m += r[4] * p45.x + r[5] * p45.y + r[6] * p67.x + r[7] * p67.y;
    }
    atomicAdd(agg + d * 32 + o, m);
}

// fused: h2 computed inline during pooling (never stored).
// batch is sorted -> contiguous node range per graph; binary search, no atomics
__global__ __launch_bounds__(256) void k7_pool(const float* __restrict__ agg2,
        const float* __restrict__ cnt, const __half* __restrict__ P2,
        const float* __restrict__ bias2, const int* __restrict__ batch,
        float* __restrict__ gp) {
    int g = blockIdx.x;
    int t = threadIdx.x;
    int lo = 0, hi = N_NODES;
    while (lo < hi) { int mid = (lo + hi) >> 1; if (batch[mid] < g) lo = mid + 1; else hi = mid; }
    int start = lo;
    hi = N_NODES;
    while (lo < hi) { int mid = (lo + hi) >> 1; if (batch[mid] < g + 1) lo = mid + 1; else hi = mid; }
    int end = lo;
    int o = t & 31, ch = t >> 5;
    float s = 0.f;
    for (int n = start + ch; n < end; n += 8) {
        float c = fmaxf(cnt[n], 1.0f);
        float v = agg2[(size_t)n * 32 + o] / c
                + __half2float(P2[(size_t)n * 384 + o * 12 + 11]) + bias2[o];
        s += v > 0.f ? v : expm1f(v);
    }
    __shared__ float red[8][32];
    red[ch][o] = s;
    __syncthreads();
    if (t < 32) {
        float tot = 0.f;
#pragma unroll
        for (int c = 0; c < 8; c++) tot += red[c][t];
        gp[g * 32 + t] = tot / fmaxf((float)(end - start), 1.0f);
    }
}

__global__ __launch_bounds__(256) void k8_head(const float* __restrict__ gp,
        const float* __restrict__ fc1w, const float* __restrict__ fc1b,
        const float* __restrict__ fc2w, const float* __restrict__ fc2b,
        float* __restrict__ out) {
    __shared__ float gl[64][32];
    __shared__ float w1l[32][64];
    __shared__ float hl[64][64];
    __shared__ float zl[64][2];
    int t = threadIdx.x;
    for (int idx = t; idx < 64 * 32; idx += 256) gl[idx >> 5][idx & 31] = gp[idx];
    for (int idx = t; idx < 32 * 64; idx += 256) w1l[idx >> 6][idx & 63] = fc1w[idx];
    __syncthreads();
    for (int idx = t; idx < 64 * 64; idx += 256) {
        int gg = idx >> 6, c = idx & 63;
        float acc = fc1b[c];
#pragma unroll
        for (int i = 0; i < 32; i++) acc += gl[gg][i] * w1l[i][c];
        hl[gg][c] = acc > 0.f ? acc : expm1f(acc);
    }
    __syncthreads();
    if (t < 128) {
        int gg = t >> 1, k = t & 1;
        float acc = fc2b[k];
#pragma unroll
        for (int c = 0; c < 64; c++) acc += hl[gg][c] * fc2w[c * 2 + k];
        zl[gg][k] = acc;
    }
    __syncthreads();
    if (t < 128) {
        int gg = t >> 1, k = t & 1;
        float z0 = zl[gg][0], z1 = zl[gg][1];
        float m = fmaxf(z0, z1);
        float lse = m + logf(expf(z0 - m) + expf(z1 - m));
        out[t] = zl[gg][k] - lse;
    }
}

extern "C" void kernel_launch(void* const* d_in, const int* in_sizes, int n_in,
                              void* d_out, int out_size, void* d_ws, size_t ws_size,
                              hipStream_t stream) {
    const float* x       = (const float*)d_in[0];
    const int*   ei      = (const int*)d_in[1];
    const float* ea      = (const float*)d_in[2];
    const int*   batch   = (const int*)d_in[3];
    const float* nn1_w1  = (const float*)d_in[4];
    const float* nn1_b1  = (const float*)d_in[5];
    const float* nn1_w2  = (const float*)d_in[6];
    const float* nn1_b2  = (const float*)d_in[7];
    const float* c1_root = (const float*)d_in[8];
    const float* c1_bias = (const float*)d_in[9];
    const float* nn2_w1  = (const float*)d_in[10];
    const float* nn2_b1  = (const float*)d_in[11];
    const float* nn2_w2  = (const float*)d_in[12];
    const float* nn2_b2  = (const float*)d_in[13];
    const float* c2_root = (const float*)d_in[14];
    const float* c2_bias = (const float*)d_in[15];
    const float* fc1w    = (const float*)d_in[16];
    const float* fc1b    = (const float*)d_in[17];
    const float* fc2w    = (const float*)d_in[18];
    const float* fc2b    = (const float*)d_in[19];
    const int* src = ei;
    const int* dst = ei + N_EDGES;

    char* ws = (char*)d_ws;
    __half* P1 = (__half*)ws;                                // 19.2 MB
    __half* P2 = (__half*)(ws + (size_t)N_NODES * 192 * 2);  // 38.4 MB
    float* fbase = (float*)(ws + (size_t)N_NODES * 192 * 2 + (size_t)N_NODES * 384 * 2);
    float* cnt  = fbase;                                     // 50000
    float* agg1 = cnt + N_NODES;                             // 800000
    float* agg2 = agg1 + (size_t)N_NODES * 16;               // 1600000
    float* gp   = agg2 + (size_t)N_NODES * 32;               // 2048

    hipMemsetAsync(cnt, 0, (size_t)(N_NODES + N_NODES * 16 + N_NODES * 32) * sizeof(float), stream);

    k1_p1<<<(N_NODES + 15) / 16, 256, 0, stream>>>(x, nn1_w2, nn1_b2, c1_root, P1);
    k2_edge1<<<(N_EDGES + 15) / 16, 256, 0, stream>>>(P1, src, dst, ea, nn1_w1, nn1_b1, agg1, cnt);
    k4_p2<<<(N_NODES + 7) / 8, 256, 0, stream>>>(agg1, cnt, P1, c1_bias, nn2_w2, nn2_b2, c2_root, P2);
    k5_edge2<<<(N_EDGES + 7) / 8, 256, 0, stream>>>(P2, src, dst, ea, nn2_w1, nn2_b1, agg2);
    k7_pool<<<NUM_GRAPHS, 256, 0, stream>>>(agg2, cnt, P2, c2_bias, batch, gp);
    k8_head<<<1, 256, 0, stream>>>(gp, fc1w, fc1b, fc2w, fc2b, (float*)d_out);
}

// Round 5
// 281.833 us; speedup vs baseline: 1.2525x; 1.1016x over previous
//
#include <hip/hip_runtime.h>
#include <hip/hip_fp16.h>
#include <math.h>

#define N_NODES 50000
#define N_EDGES 400000
#define NUM_GRAPHS 64

// ---------------------------------------------------------------------------
// Factorized NNConv, fp16 tables in COLUMN-MAJOR-PER-NODE layout:
//   msg[e,o] = sum_j relu(a_e*w1_j+b1_j) * P[src,j,o] + Q[src,o]
// P1: per node, 16 cols x 12 half items {P[j=0..9][o], Q[o], R[o]}  (384 B/row)
// P2: per node, 32 cols x 12 half items                              (768 B/row)
// R (root-term) additionally stored DENSE fp32: R1[N][16], R2[N][32] — the
// packed copy is unused (kept only for 24B alignment of the edge gather).
// Edge lane o reads its col's 24 B as 3 independent float2 loads (ILP),
// one fp32 atomic per lane. Pooling: 512-block partial-sum kernel with
// register accumulation + per-graph-change atomic flush; mean+head fused.
// ---------------------------------------------------------------------------

__global__ __launch_bounds__(256) void k1_p1(const float* __restrict__ x,
        const float* __restrict__ w2, const float* __restrict__ b2,
        const float* __restrict__ root, __half* __restrict__ P,
        float* __restrict__ R1) {
    __shared__ float Wl[32][192];   // [i][m*16+o]
    __shared__ float xl[16][32];
    int t = threadIdx.x;
    for (int idx = t; idx < 32 * 192; idx += 256) {
        int i = idx / 192, c = idx % 192;
        int m = c >> 4, o = c & 15;
        float w;
        if (m < 10)       w = w2[m * 512 + i * 16 + o];
        else if (m == 10) w = b2[i * 16 + o];
        else              w = root[i * 16 + o];
        Wl[i][c] = w;
    }
    int n0 = blockIdx.x * 16;
    for (int idx = t; idx < 16 * 32; idx += 256) {
        int nl = idx >> 5, i = idx & 31;
        int n = n0 + nl;
        xl[nl][i] = (n < N_NODES) ? x[n * 32 + i] : 0.f;
    }
    __syncthreads();
    int nl = t >> 4, o = t & 15;
    int n = n0 + nl;
    if (n >= N_NODES) return;
    float acc[12];
#pragma unroll
    for (int m = 0; m < 12; m++) acc[m] = 0.f;
#pragma unroll
    for (int i = 0; i < 32; i++) {
        float xv = xl[nl][i];
#pragma unroll
        for (int m = 0; m < 12; m++) acc[m] += xv * Wl[i][m * 16 + o];
    }
    __half2* Po = (__half2*)(P + (size_t)n * 192 + o * 12);
#pragma unroll
    for (int k = 0; k < 6; k++) Po[k] = __floats2half2_rn(acc[2 * k], acc[2 * k + 1]);
    R1[n * 16 + o] = acc[11];
}

// fused: h1 = elu(agg1/cnt + R1 + bias1) computed in prologue (never stored)
__global__ __launch_bounds__(256) void k4_p2(const float* __restrict__ agg1,
        const float* __restrict__ cnt, const float* __restrict__ R1,
        const float* __restrict__ bias1,
        const float* __restrict__ w2, const float* __restrict__ b2,
        const float* __restrict__ root, __half* __restrict__ P2,
        float* __restrict__ R2) {
    __shared__ float Wl[16][384];   // [i][m*32+o]
    __shared__ float hl[8][16];
    int t = threadIdx.x;
    for (int idx = t; idx < 16 * 384; idx += 256) {
        int i = idx / 384, c = idx % 384;
        int m = c >> 5, o = c & 31;
        float w;
        if (m < 10)       w = w2[m * 512 + i * 32 + o];
        else if (m == 10) w = b2[i * 32 + o];
        else              w = root[i * 32 + o];
        Wl[i][c] = w;
    }
    int n0 = blockIdx.x * 8;
    if (t < 128) {
        int nl = t >> 4, i = t & 15;
        int n = n0 + nl;
        float v = 0.f;
        if (n < N_NODES) {
            float c = fmaxf(cnt[n], 1.0f);
            v = agg1[n * 16 + i] / c + R1[n * 16 + i] + bias1[i];
            v = v > 0.f ? v : expm1f(v);
        }
        hl[nl][i] = v;
    }
    __syncthreads();
    int nl = t >> 5, o = t & 31;
    int n = n0 + nl;
    if (n >= N_NODES) return;
    float acc[12];
#pragma unroll
    for (int m = 0; m < 12; m++) acc[m] = 0.f;
#pragma unroll
    for (int i = 0; i < 16; i++) {
        float hv = hl[nl][i];
#pragma unroll
        for (int m = 0; m < 12; m++) acc[m] += hv * Wl[i][m * 32 + o];
    }
    __half2* Po = (__half2*)(P2 + (size_t)n * 384 + o * 12);
#pragma unroll
    for (int k = 0; k < 6; k++) Po[k] = __floats2half2_rn(acc[2 * k], acc[2 * k + 1]);
    R2[(size_t)n * 32 + o] = acc[11];
}

// conv1 edges: 16 lanes/edge, 3 independent float2 loads, 1 atomic/lane (64B/edge)
__global__ __launch_bounds__(256) void k2_edge1(const __half* __restrict__ P,
        const int* __restrict__ src, const int* __restrict__ dst,
        const float* __restrict__ ea, const float* __restrict__ w1,
        const float* __restrict__ b1, float* __restrict__ agg,
        float* __restrict__ cnt) {
    int t = threadIdx.x;
    int e = blockIdx.x * 16 + (t >> 4);
    int o = t & 15;
    if (e >= N_EDGES) return;
    float a = ea[e];
    int s = src[e], d = dst[e];
    const float2* Pf = (const float2*)P;
    int base = s * 48 + o * 3;
    float2 f0 = Pf[base];
    float2 f1 = Pf[base + 1];
    float2 f2 = Pf[base + 2];
    float r[10];
#pragma unroll
    for (int j = 0; j < 10; j++) r[j] = fmaxf(a * w1[j] + b1[j], 0.f);
    union { float2 f; __half2 h[2]; } u;
    float m;
    {
        u.f = f2;                       // items (8,9) (Q,R)
        float2 p89 = __half22float2(u.h[0]);
        float2 pQR = __half22float2(u.h[1]);
        m = pQR.x + r[8] * p89.x + r[9] * p89.y;
    }
    {
        u.f = f0;                       // items (0,1) (2,3)
        float2 p01 = __half22float2(u.h[0]);
        float2 p23 = __half22float2(u.h[1]);
        m += r[0] * p01.x + r[1] * p01.y + r[2] * p23.x + r[3] * p23.y;
    }
    {
        u.f = f1;                       // items (4,5) (6,7)
        float2 p45 = __half22float2(u.h[0]);
        float2 p67 = __half22float2(u.h[1]);
        m += r[4] * p45.x + r[5] * p45.y + r[6] * p67.x + r[7] * p67.y;
    }
    atomicAdd(agg + d * 16 + o, m);
    if (o == 0) atomicAdd(cnt + d, 1.0f);
}

// conv2 edges: 32 lanes/edge, 3 independent float2 loads, 1 atomic/lane (128B/edge)
__global__ __launch_bounds__(256) void k5_edge2(const __half* __restrict__ P,
        const int* __restrict__ src, const int* __restrict__ dst,
        const float* __restrict__ ea, const float* __restrict__ w1,
        const float* __restrict__ b1, float* __restrict__ agg) {
    int t = threadIdx.x;
    int e = blockIdx.x * 8 + (t >> 5);
    int o = t & 31;
    if (e >= N_EDGES) return;
    float a = ea[e];
    int s = src[e], d = dst[e];
    const float2* Pf = (const float2*)P;
    int base = s * 96 + o * 3;
    float2 f0 = Pf[base];
    float2 f1 = Pf[base + 1];
    float2 f2 = Pf[base + 2];
    float r[10];
#pragma unroll
    for (int j = 0; j < 10; j++) r[j] = fmaxf(a * w1[j] + b1[j], 0.f);
    union { float2 f; __half2 h[2]; } u;
    float m;
    {
        u.f = f2;
        float2 p89 = __half22float2(u.h[0]);
        float2 pQR = __half22float2(u.h[1]);
        m = pQR.x + r[8] * p89.x + r[9] * p89.y;
    }
    {
        u.f = f0;
        float2 p01 = __half22float2(u.h[0]);
        float2 p23 = __half22float2(u.h[1]);
        m += r[0] * p01.x + r[1] * p01.y + r[2] * p23.x + r[3] * p23.y;
    }
    {
        u.f = f1;
        float2 p45 = __half22float2(u.h[0]);
        float2 p67 = __half22float2(u.h[1]);
        m += r[4] * p45.x + r[5] * p45.y + r[6] * p67.x + r[7] * p67.y;
    }
    atomicAdd(agg + d * 32 + o, m);
}

// High-occupancy pooling partials: 512 blocks, 8 node-lanes x 32 cols.
// h2 computed inline; batch sorted -> register-accumulate per graph, flush
// one atomicAdd per graph change (<=2 graphs per thread chunk typically).
__global__ __launch_bounds__(256) void k6_partial(const float* __restrict__ agg2,
        const float* __restrict__ cnt, const float* __restrict__ R2,
        const float* __restrict__ bias2, const int* __restrict__ batch,
        float* __restrict__ gsum) {
    const int NB = 512;
    const int chunk = (N_NODES + NB - 1) / NB;   // 98
    int begin = blockIdx.x * chunk;
    int end = begin + chunk;
    if (end > N_NODES) end = N_NODES;
    int t = threadIdx.x;
    int o = t & 31, ch = t >> 5;
    float bz = bias2[o];
    float acc = 0.f;
    int cur_g = -1;
    for (int n = begin + ch; n < end; n += 8) {
        int g = batch[n];
        float c = fmaxf(cnt[n], 1.0f);
        float v = agg2[(size_t)n * 32 + o] / c + R2[(size_t)n * 32 + o] + bz;
        v = v > 0.f ? v : expm1f(v);
        if (g != cur_g) {
            if (cur_g >= 0) atomicAdd(gsum + cur_g * 32 + o, acc);
            cur_g = g; acc = 0.f;
        }
        acc += v;
    }
    if (cur_g >= 0) atomicAdd(gsum + cur_g * 32 + o, acc);
}

// head: mean finalize (counts via binary search on sorted batch) + fc1 + fc2 + log_softmax
__global__ __launch_bounds__(256) void k8_head(const float* __restrict__ gsum,
        const int* __restrict__ batch,
        const float* __restrict__ fc1w, const float* __restrict__ fc1b,
        const float* __restrict__ fc2w, const float* __restrict__ fc2b,
        float* __restrict__ out) {
    __shared__ float gl[64][32];
    __shared__ float w1l[32][64];
    __shared__ float hl[64][64];
    __shared__ float zl[64][2];
    __shared__ float gc[64];
    int t = threadIdx.x;
    if (t < 64) {
        int g = t;
        int lo = 0, hi = N_NODES;
        while (lo < hi) { int mid = (lo + hi) >> 1; if (batch[mid] < g) lo = mid + 1; else hi = mid; }
        int s0 = lo;
        lo = 0; hi = N_NODES;
        while (lo < hi) { int mid = (lo + hi) >> 1; if (batch[mid] < g + 1) lo = mid + 1; else hi = mid; }
        gc[g] = fmaxf((float)(lo - s0), 1.0f);
    }
    for (int idx = t; idx < 32 * 64; idx += 256) w1l[idx >> 6][idx & 63] = fc1w[idx];
    __syncthreads();
    for (int idx = t; idx < 64 * 32; idx += 256) gl[idx >> 5][idx & 31] = gsum[idx] / gc[idx >> 5];
    __syncthreads();
    for (int idx = t; idx < 64 * 64; idx += 256) {
        int gg = idx >> 6, c = idx & 63;
        float acc = fc1b[c];
#pragma unroll
        for (int i = 0; i < 32; i++) acc += gl[gg][i] * w1l[i][c];
        hl[gg][c] = acc > 0.f ? acc : expm1f(acc);
    }
    __syncthreads();
    if (t < 128) {
        int gg = t >> 1, k = t & 1;
        float acc = fc2b[k];
#pragma unroll
        for (int c = 0; c < 64; c++) acc += hl[gg][c] * fc2w[c * 2 + k];
        zl[gg][k] = acc;
    }
    __syncthreads();
    if (t < 128) {
        int gg = t >> 1, k = t & 1;
        float z0 = zl[gg][0], z1 = zl[gg][1];
        float m = fmaxf(z0, z1);
        float lse = m + logf(expf(z0 - m) + expf(z1 - m));
        out[t] = zl[gg][k] - lse;
    }
}

extern "C" void kernel_launch(void* const* d_in, const int* in_sizes, int n_in,
                              void* d_out, int out_size, void* d_ws, size_t ws_size,
                              hipStream_t stream) {
    const float* x       = (const float*)d_in[0];
    const int*   ei      = (const int*)d_in[1];
    const float* ea      = (const float*)d_in[2];
    const int*   batch   = (const int*)d_in[3];
    const float* nn1_w1  = (const float*)d_in[4];
    const float* nn1_b1  = (const float*)d_in[5];
    const float* nn1_w2  = (const float*)d_in[6];
    const float* nn1_b2  = (const float*)d_in[7];
    const float* c1_root = (const float*)d_in[8];
    const float* c1_bias = (const float*)d_in[9];
    const float* nn2_w1  = (const float*)d_in[10];
    const float* nn2_b1  = (const float*)d_in[11];
    const float* nn2_w2  = (const float*)d_in[12];
    const float* nn2_b2  = (const float*)d_in[13];
    const float* c2_root = (const float*)d_in[14];
    const float* c2_bias = (const float*)d_in[15];
    const float* fc1w    = (const float*)d_in[16];
    const float* fc1b    = (const float*)d_in[17];
    const float* fc2w    = (const float*)d_in[18];
    const float* fc2b    = (const float*)d_in[19];
    const int* src = ei;
    const int* dst = ei + N_EDGES;

    char* ws = (char*)d_ws;
    __half* P1 = (__half*)ws;                                // 19.2 MB
    __half* P2 = (__half*)(ws + (size_t)N_NODES * 192 * 2);  // 38.4 MB
    float* fbase = (float*)(ws + (size_t)N_NODES * 192 * 2 + (size_t)N_NODES * 384 * 2);
    float* cnt  = fbase;                                     // 50000
    float* agg1 = cnt + N_NODES;                             // 800000
    float* agg2 = agg1 + (size_t)N_NODES * 16;               // 1600000
    float* gsum = agg2 + (size_t)N_NODES * 32;               // 2048
    float* R1   = gsum + NUM_GRAPHS * 32;                    // 800000
    float* R2   = R1 + (size_t)N_NODES * 16;                 // 1600000

    // cnt, agg1, agg2, gsum contiguous: one memset (R1/R2 fully written before read)
    hipMemsetAsync(cnt, 0,
        (size_t)(N_NODES + N_NODES * 16 + N_NODES * 32 + NUM_GRAPHS * 32) * sizeof(float), stream);

    k1_p1<<<(N_NODES + 15) / 16, 256, 0, stream>>>(x, nn1_w2, nn1_b2, c1_root, P1, R1);
    k2_edge1<<<(N_EDGES + 15) / 16, 256, 0, stream>>>(P1, src, dst, ea, nn1_w1, nn1_b1, agg1, cnt);
    k4_p2<<<(N_NODES + 7) / 8, 256, 0, stream>>>(agg1, cnt, R1, c1_bias, nn2_w2, nn2_b2, c2_root, P2, R2);
    k5_edge2<<<(N_EDGES + 7) / 8, 256, 0, stream>>>(P2, src, dst, ea, nn2_w1, nn2_b1, agg2);
    k6_partial<<<512, 256, 0, stream>>>(agg2, cnt, R2, c2_bias, batch, gsum);
    k8_head<<<1, 256, 0, stream>>>(gsum, batch, fc1w, fc1b, fc2w, fc2b, (float*)d_out);
}